// Round 1
// baseline (372.387 us; speedup 1.0000x reference)
//
#include <hip/hip_runtime.h>

#define N_NODES 50000
#define N_EDGES 800000
#define D 64
#define SCAN_BLOCKS 49   // ceil(50000/1024)

// ---------------- degree histogram ----------------
__global__ void k_deg(const int* __restrict__ dst, int* __restrict__ deg) {
    int e = blockIdx.x * blockDim.x + threadIdx.x;
    if (e < N_EDGES) atomicAdd(&deg[dst[e]], 1);
}

// ---------------- hierarchical exclusive scan ----------------
__global__ void k_scan1(const int* __restrict__ deg, int* __restrict__ rowoff,
                        int* __restrict__ blocksums) {
    __shared__ int tile[1024];
    int tid = threadIdx.x;
    int i = blockIdx.x * 1024 + tid;
    int v = (i < N_NODES) ? deg[i] : 0;
    tile[tid] = v;
    __syncthreads();
    for (int off = 1; off < 1024; off <<= 1) {
        int add = (tid >= off) ? tile[tid - off] : 0;
        __syncthreads();
        tile[tid] += add;
        __syncthreads();
    }
    if (i < N_NODES) rowoff[i] = tile[tid] - v;     // block-local exclusive
    if (tid == 1023) blocksums[blockIdx.x] = tile[1023];
}

__global__ void k_scan2(const int* __restrict__ blocksums, int* __restrict__ blockoffs,
                        int* __restrict__ rowoff) {
    int lane = threadIdx.x;  // 64 threads, 1 wave
    int v = (lane < SCAN_BLOCKS) ? blocksums[lane] : 0;
    int incl = v;
    for (int off = 1; off < 64; off <<= 1) {
        int u = __shfl_up(incl, off, 64);
        if (lane >= off) incl += u;
    }
    if (lane < SCAN_BLOCKS) blockoffs[lane] = incl - v;
    if (lane == 63) rowoff[N_NODES] = incl;          // grand total (= N_EDGES)
}

__global__ void k_scan3(int* __restrict__ rowoff, const int* __restrict__ blockoffs) {
    int i = blockIdx.x * 1024 + threadIdx.x;
    if (i < N_NODES) rowoff[i] += blockoffs[blockIdx.x];
}

// ---------------- CSR fill (group src indices by dst) ----------------
__global__ void k_fill(const int* __restrict__ src, const int* __restrict__ dst,
                       const int* __restrict__ rowoff, int* __restrict__ fillcnt,
                       int* __restrict__ csr) {
    int e = blockIdx.x * blockDim.x + threadIdx.x;
    if (e < N_EDGES) {
        int d = dst[e];
        int p = atomicAdd(&fillcnt[d], 1);
        csr[rowoff[d] + p] = src[e];
    }
}

// ---------------- mean aggregation: one wave per node, lane = feature ----------------
__global__ __launch_bounds__(256) void k_agg(const float* __restrict__ h,
                                             const int* __restrict__ rowoff,
                                             const int* __restrict__ csr,
                                             float* __restrict__ agg) {
    int wave = (blockIdx.x * blockDim.x + threadIdx.x) >> 6;
    int lane = threadIdx.x & 63;
    if (wave >= N_NODES) return;
    int start = rowoff[wave], end = rowoff[wave + 1];
    float s = 0.f;
    int e = start;
    for (; e + 4 <= end; e += 4) {
        int s0 = csr[e], s1 = csr[e + 1], s2 = csr[e + 2], s3 = csr[e + 3];
        s += h[s0 * D + lane] + h[s1 * D + lane] + h[s2 * D + lane] + h[s3 * D + lane];
    }
    for (; e < end; ++e) s += h[csr[e] * D + lane];
    float inv = 1.0f / fmaxf((float)(end - start), 1.0f);
    agg[wave * D + lane] = s * inv;
}

// ---------------- combine: out = hin@Ws + agg@Wn + b (+relu) ----------------
// Lane j holds columns Ws[:,j], Wn[:,j] in registers; row elements broadcast via shfl.
__global__ __launch_bounds__(256) void k_combine(const float* __restrict__ hin,
                                                 const float* __restrict__ agg,
                                                 const float* __restrict__ Ws,
                                                 const float* __restrict__ Wn,
                                                 const float* __restrict__ b,
                                                 float* __restrict__ out, int relu) {
    int lane = threadIdx.x & 63;
    int gwave = (blockIdx.x * blockDim.x + threadIdx.x) >> 6;
    int nwaves = (gridDim.x * blockDim.x) >> 6;

    float ws[D], wn[D];
#pragma unroll
    for (int k = 0; k < D; ++k) {
        ws[k] = Ws[k * D + lane];
        wn[k] = Wn[k * D + lane];
    }
    float bj = b[lane];

    for (int i = gwave; i < N_NODES; i += nwaves) {
        float xv = hin[i * D + lane];
        float av = agg[i * D + lane];
        float a0 = bj, a1 = 0.f, a2 = 0.f, a3 = 0.f;
#pragma unroll
        for (int k = 0; k < D; k += 2) {
            a0 = fmaf(__shfl(xv, k, 64),     ws[k],     a0);
            a1 = fmaf(__shfl(av, k, 64),     wn[k],     a1);
            a2 = fmaf(__shfl(xv, k + 1, 64), ws[k + 1], a2);
            a3 = fmaf(__shfl(av, k + 1, 64), wn[k + 1], a3);
        }
        float acc = (a0 + a1) + (a2 + a3);
        if (relu) acc = fmaxf(acc, 0.f);
        out[i * D + lane] = acc;   // in-place safe: row read before write
    }
}

extern "C" void kernel_launch(void* const* d_in, const int* in_sizes, int n_in,
                              void* d_out, int out_size, void* d_ws, size_t ws_size,
                              hipStream_t stream) {
    const float* x   = (const float*)d_in[0];
    const int*   src = (const int*)d_in[1];
    const int*   dst = (const int*)d_in[2];
    const float* Ws0 = (const float*)d_in[3];
    const float* Wn0 = (const float*)d_in[4];
    const float* b0  = (const float*)d_in[5];
    const float* Ws1 = (const float*)d_in[6];
    const float* Wn1 = (const float*)d_in[7];
    const float* b1  = (const float*)d_in[8];
    float* out = (float*)d_out;

    // workspace layout
    char* p = (char*)d_ws;
    float* agg      = (float*)p;                 p += (size_t)N_NODES * D * sizeof(float);
    int*   deg      = (int*)p;                   p += (size_t)N_NODES * sizeof(int);
    int*   fillcnt  = (int*)p;                   p += (size_t)N_NODES * sizeof(int);
    int*   rowoff   = (int*)p;                   p += (size_t)(N_NODES + 1) * sizeof(int);
    int*   blocksums= (int*)p;                   p += 64 * sizeof(int);
    int*   blockoffs= (int*)p;                   p += 64 * sizeof(int);
    int*   csr      = (int*)p;                   p += (size_t)N_EDGES * sizeof(int);

    // zero the counters (deg + fillcnt are adjacent)
    hipMemsetAsync(deg, 0, 2 * (size_t)N_NODES * sizeof(int), stream);

    // build CSR (dst-grouped src lists)
    k_deg<<<(N_EDGES + 255) / 256, 256, 0, stream>>>(dst, deg);
    k_scan1<<<SCAN_BLOCKS, 1024, 0, stream>>>(deg, rowoff, blocksums);
    k_scan2<<<1, 64, 0, stream>>>(blocksums, blockoffs, rowoff);
    k_scan3<<<SCAN_BLOCKS, 1024, 0, stream>>>(rowoff, blockoffs);
    k_fill<<<(N_EDGES + 255) / 256, 256, 0, stream>>>(src, dst, rowoff, fillcnt, csr);

    const int aggBlocks = (N_NODES + 3) / 4;     // 4 waves (nodes) per 256-thread block

    // layer 0: h = relu(x@Ws0 + mean_agg(x)@Wn0 + b0), h stored in d_out
    k_agg<<<aggBlocks, 256, 0, stream>>>(x, rowoff, csr, agg);
    k_combine<<<1024, 256, 0, stream>>>(x, agg, Ws0, Wn0, b0, out, 1);

    // layer 1: out = h@Ws1 + mean_agg(h)@Wn1 + b1 (no relu)
    k_agg<<<aggBlocks, 256, 0, stream>>>(out, rowoff, csr, agg);
    k_combine<<<1024, 256, 0, stream>>>(out, agg, Ws1, Wn1, b1, out, 0);
}

// Round 2
// 266.953 us; speedup vs baseline: 1.3950x; 1.3950x over previous
//
#include <hip/hip_runtime.h>

#define N_NODES 50000
#define N_EDGES 800000
#define D 64
#define SCAN_BLOCKS 49   // ceil(50000/1024)

// ---------------- degree histogram ----------------
__global__ void k_deg(const int* __restrict__ dst, int* __restrict__ deg) {
    int e = blockIdx.x * blockDim.x + threadIdx.x;
    if (e < N_EDGES) atomicAdd(&deg[dst[e]], 1);
}

// ---------------- hierarchical exclusive scan ----------------
__global__ void k_scan1(const int* __restrict__ deg, int* __restrict__ rowoff,
                        int* __restrict__ blocksums) {
    __shared__ int tile[1024];
    int tid = threadIdx.x;
    int i = blockIdx.x * 1024 + tid;
    int v = (i < N_NODES) ? deg[i] : 0;
    tile[tid] = v;
    __syncthreads();
    for (int off = 1; off < 1024; off <<= 1) {
        int add = (tid >= off) ? tile[tid - off] : 0;
        __syncthreads();
        tile[tid] += add;
        __syncthreads();
    }
    if (i < N_NODES) rowoff[i] = tile[tid] - v;     // block-local exclusive
    if (tid == 1023) blocksums[blockIdx.x] = tile[1023];
}

__global__ void k_scan2(const int* __restrict__ blocksums, int* __restrict__ blockoffs,
                        int* __restrict__ rowoff) {
    int lane = threadIdx.x;  // 64 threads, 1 wave
    int v = (lane < SCAN_BLOCKS) ? blocksums[lane] : 0;
    int incl = v;
    for (int off = 1; off < 64; off <<= 1) {
        int u = __shfl_up(incl, off, 64);
        if (lane >= off) incl += u;
    }
    if (lane < SCAN_BLOCKS) blockoffs[lane] = incl - v;
    if (lane == 63) rowoff[N_NODES] = incl;          // grand total (= N_EDGES)
}

__global__ void k_scan3(int* __restrict__ rowoff, const int* __restrict__ blockoffs) {
    int i = blockIdx.x * 1024 + threadIdx.x;
    if (i < N_NODES) rowoff[i] += blockoffs[blockIdx.x];
}

// ---------------- CSR fill (group src indices by dst) ----------------
__global__ void k_fill(const int* __restrict__ src, const int* __restrict__ dst,
                       const int* __restrict__ rowoff, int* __restrict__ fillcnt,
                       int* __restrict__ csr) {
    int e = blockIdx.x * blockDim.x + threadIdx.x;
    if (e < N_EDGES) {
        int d = dst[e];
        int p = atomicAdd(&fillcnt[d], 1);
        csr[rowoff[d] + p] = src[e];
    }
}

// ---------------- transform: yS = h@Ws + b, yN = h@Wn ----------------
// Wave-specialized (even waves -> Ws/yS, odd -> Wn/yN). Lane = output column,
// W column held in 64 VGPRs. Row elements of h are read as wave-uniform
// float4 loads (readfirstlane-forced uniform wave id -> scalarizable), so no
// v_readlane chains; 4 rows per iteration give 4 independent FMA chains.
__global__ __launch_bounds__(256, 4) void k_xform(const float* __restrict__ h,
        const float* __restrict__ Ws, const float* __restrict__ Wn,
        const float* __restrict__ b,
        float* __restrict__ yS, float* __restrict__ yN) {
    int lane = threadIdx.x & 63;
    int gwave = __builtin_amdgcn_readfirstlane((blockIdx.x * blockDim.x + threadIdx.x) >> 6);
    int nwaves = (gridDim.x * blockDim.x) >> 6;

    int mat = gwave & 1;
    const float* W = mat ? Wn : Ws;
    float* Y = mat ? yN : yS;

    float w[D];
#pragma unroll
    for (int k = 0; k < D; ++k) w[k] = W[k * D + lane];
    float bj = mat ? 0.f : b[lane];

    const int ngroups = (N_NODES + 3) / 4;   // 12500, exact
    for (int g = gwave >> 1; g < ngroups; g += (nwaves >> 1)) {
        const float* x0 = h + (size_t)(g * 4) * D;
        float a0 = bj, a1 = bj, a2 = bj, a3 = bj;
#pragma unroll
        for (int kq = 0; kq < 16; ++kq) {
            float4 v0 = *(const float4*)(x0 + 0 * D + kq * 4);
            float4 v1 = *(const float4*)(x0 + 1 * D + kq * 4);
            float4 v2 = *(const float4*)(x0 + 2 * D + kq * 4);
            float4 v3 = *(const float4*)(x0 + 3 * D + kq * 4);
            a0 = fmaf(v0.x, w[kq * 4 + 0], a0);
            a1 = fmaf(v1.x, w[kq * 4 + 0], a1);
            a2 = fmaf(v2.x, w[kq * 4 + 0], a2);
            a3 = fmaf(v3.x, w[kq * 4 + 0], a3);
            a0 = fmaf(v0.y, w[kq * 4 + 1], a0);
            a1 = fmaf(v1.y, w[kq * 4 + 1], a1);
            a2 = fmaf(v2.y, w[kq * 4 + 1], a2);
            a3 = fmaf(v3.y, w[kq * 4 + 1], a3);
            a0 = fmaf(v0.z, w[kq * 4 + 2], a0);
            a1 = fmaf(v1.z, w[kq * 4 + 2], a1);
            a2 = fmaf(v2.z, w[kq * 4 + 2], a2);
            a3 = fmaf(v3.z, w[kq * 4 + 2], a3);
            a0 = fmaf(v0.w, w[kq * 4 + 3], a0);
            a1 = fmaf(v1.w, w[kq * 4 + 3], a1);
            a2 = fmaf(v2.w, w[kq * 4 + 3], a2);
            a3 = fmaf(v3.w, w[kq * 4 + 3], a3);
        }
        size_t base = (size_t)(g * 4) * D + lane;
        Y[base + 0 * D] = a0;
        Y[base + 1 * D] = a1;
        Y[base + 2 * D] = a2;
        Y[base + 3 * D] = a3;
    }
}

// ---------------- fused mean-aggregate + self + bias'd epilogue ----------------
// out[i] = act(yS[i] + (1/deg_i) * sum_{e: dst=i} yN[src_e])
__global__ __launch_bounds__(256) void k_aggf(const float* __restrict__ yN,
        const float* __restrict__ yS,
        const int* __restrict__ rowoff, const int* __restrict__ csr,
        float* __restrict__ out, int relu) {
    int node = __builtin_amdgcn_readfirstlane((blockIdx.x * blockDim.x + threadIdx.x) >> 6);
    int lane = threadIdx.x & 63;
    if (node >= N_NODES) return;
    int start = rowoff[node], end = rowoff[node + 1];
    float self = yS[(size_t)node * D + lane];
    float s = 0.f;
    int e = start;
    for (; e + 4 <= end; e += 4) {
        int s0 = csr[e], s1 = csr[e + 1], s2 = csr[e + 2], s3 = csr[e + 3];
        s += yN[(size_t)s0 * D + lane] + yN[(size_t)s1 * D + lane] +
             yN[(size_t)s2 * D + lane] + yN[(size_t)s3 * D + lane];
    }
    for (; e < end; ++e) s += yN[(size_t)csr[e] * D + lane];
    float inv = 1.0f / fmaxf((float)(end - start), 1.0f);
    float acc = self + s * inv;
    if (relu) acc = fmaxf(acc, 0.f);
    out[(size_t)node * D + lane] = acc;
}

extern "C" void kernel_launch(void* const* d_in, const int* in_sizes, int n_in,
                              void* d_out, int out_size, void* d_ws, size_t ws_size,
                              hipStream_t stream) {
    const float* x   = (const float*)d_in[0];
    const int*   src = (const int*)d_in[1];
    const int*   dst = (const int*)d_in[2];
    const float* Ws0 = (const float*)d_in[3];
    const float* Wn0 = (const float*)d_in[4];
    const float* b0  = (const float*)d_in[5];
    const float* Ws1 = (const float*)d_in[6];
    const float* Wn1 = (const float*)d_in[7];
    const float* b1  = (const float*)d_in[8];
    float* out = (float*)d_out;

    // workspace layout
    char* p = (char*)d_ws;
    float* yS       = (float*)p;                 p += (size_t)N_NODES * D * sizeof(float);
    float* yN       = (float*)p;                 p += (size_t)N_NODES * D * sizeof(float);
    int*   deg      = (int*)p;                   p += (size_t)N_NODES * sizeof(int);
    int*   fillcnt  = (int*)p;                   p += (size_t)N_NODES * sizeof(int);
    int*   rowoff   = (int*)p;                   p += (size_t)(N_NODES + 1) * sizeof(int);
    int*   blocksums= (int*)p;                   p += 64 * sizeof(int);
    int*   blockoffs= (int*)p;                   p += 64 * sizeof(int);
    int*   csr      = (int*)p;                   p += (size_t)N_EDGES * sizeof(int);

    // zero the counters (deg + fillcnt are adjacent)
    hipMemsetAsync(deg, 0, 2 * (size_t)N_NODES * sizeof(int), stream);

    // build CSR (dst-grouped src lists)
    k_deg<<<(N_EDGES + 255) / 256, 256, 0, stream>>>(dst, deg);
    k_scan1<<<SCAN_BLOCKS, 1024, 0, stream>>>(deg, rowoff, blocksums);
    k_scan2<<<1, 64, 0, stream>>>(blocksums, blockoffs, rowoff);
    k_scan3<<<SCAN_BLOCKS, 1024, 0, stream>>>(rowoff, blockoffs);
    k_fill<<<(N_EDGES + 255) / 256, 256, 0, stream>>>(src, dst, rowoff, fillcnt, csr);

    const int aggBlocks = (N_NODES + 3) / 4;     // wave per node, 4 per block

    // layer 0: yS0 = x@Ws0+b0, yN0 = x@Wn0; h = relu(yS0 + mean-gather(yN0)) -> d_out
    k_xform<<<1024, 256, 0, stream>>>(x, Ws0, Wn0, b0, yS, yN);
    k_aggf<<<aggBlocks, 256, 0, stream>>>(yN, yS, rowoff, csr, out, 1);

    // layer 1: same with h = d_out, no relu, final -> d_out
    k_xform<<<1024, 256, 0, stream>>>(out, Ws1, Wn1, b1, yS, yN);
    k_aggf<<<aggBlocks, 256, 0, stream>>>(yN, yS, rowoff, csr, out, 0);
}

// Round 3
// 264.218 us; speedup vs baseline: 1.4094x; 1.0103x over previous
//
#include <hip/hip_runtime.h>

#define N_NODES 50000
#define N_EDGES 800000
#define D 64
#define SCAN_BLOCKS 49   // ceil(50000/1024)
#define NSLICE 8
#define SLICE_N ((N_NODES + NSLICE - 1) / NSLICE)   // 6250

// ---------------- degree histogram (XCD-partitioned by dst slice) ----------------
// Block group g = blockIdx&7 processes only dst in [g*SLICE_N, (g+1)*SLICE_N):
// keeps each deg[] cache line dirty in exactly one XCD's L2.
__global__ __launch_bounds__(256) void k_deg(const int* __restrict__ dst,
                                             int* __restrict__ deg) {
    int slice = blockIdx.x & (NSLICE - 1);
    int lo = slice * SLICE_N, hi = lo + SLICE_N;
    int gblk = blockIdx.x >> 3, nblk = gridDim.x >> 3;
    for (int e = gblk * blockDim.x + threadIdx.x; e < N_EDGES; e += nblk * blockDim.x) {
        int d = dst[e];
        if (d >= lo && d < hi) atomicAdd(&deg[d], 1);
    }
}

// ---------------- hierarchical exclusive scan ----------------
__global__ void k_scan1(const int* __restrict__ deg, int* __restrict__ rowoff,
                        int* __restrict__ blocksums) {
    __shared__ int tile[1024];
    int tid = threadIdx.x;
    int i = blockIdx.x * 1024 + tid;
    int v = (i < N_NODES) ? deg[i] : 0;
    tile[tid] = v;
    __syncthreads();
    for (int off = 1; off < 1024; off <<= 1) {
        int add = (tid >= off) ? tile[tid - off] : 0;
        __syncthreads();
        tile[tid] += add;
        __syncthreads();
    }
    if (i < N_NODES) rowoff[i] = tile[tid] - v;     // block-local exclusive
    if (tid == 1023) blocksums[blockIdx.x] = tile[1023];
}

__global__ void k_scan2(const int* __restrict__ blocksums, int* __restrict__ blockoffs,
                        int* __restrict__ rowoff) {
    int lane = threadIdx.x;  // 64 threads, 1 wave
    int v = (lane < SCAN_BLOCKS) ? blocksums[lane] : 0;
    int incl = v;
    for (int off = 1; off < 64; off <<= 1) {
        int u = __shfl_up(incl, off, 64);
        if (lane >= off) incl += u;
    }
    if (lane < SCAN_BLOCKS) blockoffs[lane] = incl - v;
    if (lane == 63) rowoff[N_NODES] = incl;          // grand total (= N_EDGES)
}

__global__ void k_scan3(int* __restrict__ rowoff, const int* __restrict__ blockoffs) {
    int i = blockIdx.x * 1024 + threadIdx.x;
    if (i < N_NODES) rowoff[i] += blockoffs[blockIdx.x];
}

// ---------------- CSR fill (XCD-partitioned by dst slice) ----------------
// Same partitioning as k_deg: all stores into csr[rowoff[lo]..rowoff[hi]) come
// from one block group -> csr lines fill completely in one L2 before a single
// writeback (R2 showed 55 MB HBM writes for a 3.2 MB array without this).
__global__ __launch_bounds__(256) void k_fill(const int* __restrict__ src,
                                              const int* __restrict__ dst,
                                              const int* __restrict__ rowoff,
                                              int* __restrict__ fillcnt,
                                              int* __restrict__ csr) {
    int slice = blockIdx.x & (NSLICE - 1);
    int lo = slice * SLICE_N, hi = lo + SLICE_N;
    int gblk = blockIdx.x >> 3, nblk = gridDim.x >> 3;
    for (int e = gblk * blockDim.x + threadIdx.x; e < N_EDGES; e += nblk * blockDim.x) {
        int d = dst[e];
        if (d >= lo && d < hi) {
            int p = atomicAdd(&fillcnt[d], 1);
            csr[rowoff[d] + p] = src[e];
        }
    }
}

// ---------------- transform: yS = h@Ws + b, yN = h@Wn ----------------
// Wave-specialized (even waves -> Ws/yS, odd -> Wn/yN). Lane = output column,
// W column held in 64 VGPRs; h rows read as wave-uniform float4 (scalarizable).
__global__ __launch_bounds__(256, 4) void k_xform(const float* __restrict__ h,
        const float* __restrict__ Ws, const float* __restrict__ Wn,
        const float* __restrict__ b,
        float* __restrict__ yS, float* __restrict__ yN) {
    int lane = threadIdx.x & 63;
    int gwave = __builtin_amdgcn_readfirstlane((blockIdx.x * blockDim.x + threadIdx.x) >> 6);
    int nwaves = (gridDim.x * blockDim.x) >> 6;

    int mat = gwave & 1;
    const float* W = mat ? Wn : Ws;
    float* Y = mat ? yN : yS;

    float w[D];
#pragma unroll
    for (int k = 0; k < D; ++k) w[k] = W[k * D + lane];
    float bj = mat ? 0.f : b[lane];

    const int ngroups = (N_NODES + 3) / 4;   // 12500, exact
    for (int g = gwave >> 1; g < ngroups; g += (nwaves >> 1)) {
        const float* x0 = h + (size_t)(g * 4) * D;
        float a0 = bj, a1 = bj, a2 = bj, a3 = bj;
#pragma unroll
        for (int kq = 0; kq < 16; ++kq) {
            float4 v0 = *(const float4*)(x0 + 0 * D + kq * 4);
            float4 v1 = *(const float4*)(x0 + 1 * D + kq * 4);
            float4 v2 = *(const float4*)(x0 + 2 * D + kq * 4);
            float4 v3 = *(const float4*)(x0 + 3 * D + kq * 4);
            a0 = fmaf(v0.x, w[kq * 4 + 0], a0);
            a1 = fmaf(v1.x, w[kq * 4 + 0], a1);
            a2 = fmaf(v2.x, w[kq * 4 + 0], a2);
            a3 = fmaf(v3.x, w[kq * 4 + 0], a3);
            a0 = fmaf(v0.y, w[kq * 4 + 1], a0);
            a1 = fmaf(v1.y, w[kq * 4 + 1], a1);
            a2 = fmaf(v2.y, w[kq * 4 + 1], a2);
            a3 = fmaf(v3.y, w[kq * 4 + 1], a3);
            a0 = fmaf(v0.z, w[kq * 4 + 2], a0);
            a1 = fmaf(v1.z, w[kq * 4 + 2], a1);
            a2 = fmaf(v2.z, w[kq * 4 + 2], a2);
            a3 = fmaf(v3.z, w[kq * 4 + 2], a3);
            a0 = fmaf(v0.w, w[kq * 4 + 3], a0);
            a1 = fmaf(v1.w, w[kq * 4 + 3], a1);
            a2 = fmaf(v2.w, w[kq * 4 + 3], a2);
            a3 = fmaf(v3.w, w[kq * 4 + 3], a3);
        }
        size_t base = (size_t)(g * 4) * D + lane;
        Y[base + 0 * D] = a0;
        Y[base + 1 * D] = a1;
        Y[base + 2 * D] = a2;
        Y[base + 3 * D] = a3;
    }
}

// ---------------- fused mean-aggregate + self + epilogue ----------------
// out[i] = act(yS[i] + (1/deg_i) * sum_{e: dst=i} yN[src_e]); 8-deep gather unroll.
__global__ __launch_bounds__(256) void k_aggf(const float* __restrict__ yN,
        const float* __restrict__ yS,
        const int* __restrict__ rowoff, const int* __restrict__ csr,
        float* __restrict__ out, int relu) {
    int node = __builtin_amdgcn_readfirstlane((blockIdx.x * blockDim.x + threadIdx.x) >> 6);
    int lane = threadIdx.x & 63;
    if (node >= N_NODES) return;
    int start = rowoff[node], end = rowoff[node + 1];
    float self = yS[(size_t)node * D + lane];
    float s0 = 0.f, s1 = 0.f;
    int e = start;
    for (; e + 8 <= end; e += 8) {
        int i0 = csr[e],     i1 = csr[e + 1], i2 = csr[e + 2], i3 = csr[e + 3];
        int i4 = csr[e + 4], i5 = csr[e + 5], i6 = csr[e + 6], i7 = csr[e + 7];
        s0 += yN[(size_t)i0 * D + lane] + yN[(size_t)i1 * D + lane] +
              yN[(size_t)i2 * D + lane] + yN[(size_t)i3 * D + lane];
        s1 += yN[(size_t)i4 * D + lane] + yN[(size_t)i5 * D + lane] +
              yN[(size_t)i6 * D + lane] + yN[(size_t)i7 * D + lane];
    }
    for (; e + 4 <= end; e += 4) {
        int i0 = csr[e], i1 = csr[e + 1], i2 = csr[e + 2], i3 = csr[e + 3];
        s0 += yN[(size_t)i0 * D + lane] + yN[(size_t)i1 * D + lane] +
              yN[(size_t)i2 * D + lane] + yN[(size_t)i3 * D + lane];
    }
    for (; e < end; ++e) s0 += yN[(size_t)csr[e] * D + lane];
    float inv = 1.0f / fmaxf((float)(end - start), 1.0f);
    float acc = self + (s0 + s1) * inv;
    if (relu) acc = fmaxf(acc, 0.f);
    out[(size_t)node * D + lane] = acc;
}

extern "C" void kernel_launch(void* const* d_in, const int* in_sizes, int n_in,
                              void* d_out, int out_size, void* d_ws, size_t ws_size,
                              hipStream_t stream) {
    const float* x   = (const float*)d_in[0];
    const int*   src = (const int*)d_in[1];
    const int*   dst = (const int*)d_in[2];
    const float* Ws0 = (const float*)d_in[3];
    const float* Wn0 = (const float*)d_in[4];
    const float* b0  = (const float*)d_in[5];
    const float* Ws1 = (const float*)d_in[6];
    const float* Wn1 = (const float*)d_in[7];
    const float* b1  = (const float*)d_in[8];
    float* out = (float*)d_out;

    // workspace layout
    char* p = (char*)d_ws;
    float* yS       = (float*)p;                 p += (size_t)N_NODES * D * sizeof(float);
    float* yN       = (float*)p;                 p += (size_t)N_NODES * D * sizeof(float);
    int*   deg      = (int*)p;                   p += (size_t)N_NODES * sizeof(int);
    int*   fillcnt  = (int*)p;                   p += (size_t)N_NODES * sizeof(int);
    int*   rowoff   = (int*)p;                   p += (size_t)(N_NODES + 1) * sizeof(int);
    int*   blocksums= (int*)p;                   p += 64 * sizeof(int);
    int*   blockoffs= (int*)p;                   p += 64 * sizeof(int);
    int*   csr      = (int*)p;                   p += (size_t)N_EDGES * sizeof(int);

    // zero the counters (deg + fillcnt are adjacent)
    hipMemsetAsync(deg, 0, 2 * (size_t)N_NODES * sizeof(int), stream);

    // build CSR (dst-grouped src lists)
    k_deg<<<1024, 256, 0, stream>>>(dst, deg);
    k_scan1<<<SCAN_BLOCKS, 1024, 0, stream>>>(deg, rowoff, blocksums);
    k_scan2<<<1, 64, 0, stream>>>(blocksums, blockoffs, rowoff);
    k_scan3<<<SCAN_BLOCKS, 1024, 0, stream>>>(rowoff, blockoffs);
    k_fill<<<1024, 256, 0, stream>>>(src, dst, rowoff, fillcnt, csr);

    const int aggBlocks = (N_NODES + 3) / 4;     // wave per node, 4 per block

    // layer 0: yS0 = x@Ws0+b0, yN0 = x@Wn0; h = relu(yS0 + mean-gather(yN0)) -> d_out
    k_xform<<<1024, 256, 0, stream>>>(x, Ws0, Wn0, b0, yS, yN);
    k_aggf<<<aggBlocks, 256, 0, stream>>>(yN, yS, rowoff, csr, out, 1);

    // layer 1: same with h = d_out, no relu, final -> d_out
    k_xform<<<1024, 256, 0, stream>>>(out, Ws1, Wn1, b1, yS, yN);
    k_aggf<<<aggBlocks, 256, 0, stream>>>(yN, yS, rowoff, csr, out, 0);
}